// Round 8
// baseline (41.841 us; speedup 1.0000x reference)
//
#include <hip/hip_runtime.h>
#include <math.h>

#define N_TOK 8192
#define DIM   4096
#define NEXP  8
#define NBLK  256                        // persistent: one block per CU
#define TPB   (N_TOK / NBLK)             // 32 tokens per block
#define TPWV  (TPB / 4)                  // 8 tokens per wave
#define PHASES 4                         // D split into 4 x 1024 floats
#define JJ     4                         // 4 iters of 256 floats per phase

typedef float f4 __attribute__((ext_vector_type(4)));   // native vec for nt loads

// Persistent single-kernel router.
//  - w (128 KB) staged to LDS once; ONE barrier total.
//  - per phase: w-slice hoisted LDS->registers (reused by all 8 tokens),
//    x burst (32 x dwordx4, nontemporal) issued in consumption order so the
//    compiler's counted vmcnt waits leave the stream in flight.
//  - no K2, no partials: butterfly + top-2 + renorm + store in-kernel.
__global__ __launch_bounds__(256, 1) void router_kernel(
    const float* __restrict__ x,   // [N_TOK, DIM]
    const float* __restrict__ w,   // [NEXP, DIM]
    float* __restrict__ out)       // [N_TOK*8] combine ++ [N_TOK*2] idx-as-float
{
    __shared__ float wl[NEXP][DIM];      // 128 KB

    const int tid  = threadIdx.x;
    const int lane = tid & 63;
    const int wid  = tid >> 6;           // 0..3
    const int n0   = blockIdx.x * TPB + wid * TPWV;

    // ---- stage all of w -> LDS (32 float4 per thread), once ----
    #pragma unroll
    for (int e = 0; e < NEXP; ++e) {
        #pragma unroll
        for (int p = 0; p < 4; ++p) {
            const int pos = p * 1024 + tid * 4;
            *(float4*)&wl[e][pos] = *(const float4*)(w + (size_t)e * DIM + pos);
        }
    }
    __syncthreads();   // the ONLY barrier

    float acc[TPWV][NEXP];
    #pragma unroll
    for (int t = 0; t < TPWV; ++t)
        #pragma unroll
        for (int e = 0; e < NEXP; ++e) acc[t][e] = 0.0f;

    const float* xr = x + (size_t)n0 * DIM + lane * 4;   // token t at xr + t*DIM

    #pragma unroll 1   // keep code size ~1 phase (I-cache); inner loops static
    for (int jb = 0; jb < PHASES; ++jb) {
        const int dpo = jb * 1024;

        // x burst: token-major = consumption order; nontemporal (zero reuse)
        f4 xq[TPWV][JJ];
        #pragma unroll
        for (int t = 0; t < TPWV; ++t)
            #pragma unroll
            for (int jj = 0; jj < JJ; ++jj)
                xq[t][jj] = __builtin_nontemporal_load(
                    (const f4*)(xr + (size_t)t * DIM + dpo + jj * 256));

        // hoist this phase's w slice LDS->registers (reused by all 8 tokens)
        f4 wq[JJ][NEXP];
        #pragma unroll
        for (int jj = 0; jj < JJ; ++jj)
            #pragma unroll
            for (int e = 0; e < NEXP; ++e)
                wq[jj][e] = *(const f4*)&wl[e][dpo + jj * 256 + lane * 4];

        #pragma unroll
        for (int t = 0; t < TPWV; ++t) {
            #pragma unroll
            for (int jj = 0; jj < JJ; ++jj) {
                const f4 xv = xq[t][jj];
                #pragma unroll
                for (int e = 0; e < NEXP; ++e) {
                    const f4 wv = wq[jj][e];
                    acc[t][e] = fmaf(xv.x, wv.x,
                                fmaf(xv.y, wv.y,
                                fmaf(xv.z, wv.z,
                                fmaf(xv.w, wv.w, acc[t][e]))));
                }
            }
        }
    }

    // ---- 64-lane butterfly: every lane gets the full logit ----
    #pragma unroll
    for (int t = 0; t < TPWV; ++t) {
        #pragma unroll
        for (int e = 0; e < NEXP; ++e) {
            float v = acc[t][e];
            #pragma unroll
            for (int off = 32; off >= 1; off >>= 1)
                v += __shfl_xor(v, off, 64);
            acc[t][e] = v;
        }
    }

    // ---- top-2 + renorm (denominator cancels) + store ----
    #pragma unroll
    for (int t = 0; t < TPWV; ++t) {
        // argmax: strict >, ascending scan => lowest index wins ties (lax.top_k)
        float m1 = acc[t][0]; int i1 = 0;
        #pragma unroll
        for (int e = 1; e < NEXP; ++e)
            if (acc[t][e] > m1) { m1 = acc[t][e]; i1 = e; }
        float m2 = -INFINITY; int i2 = 0;
        #pragma unroll
        for (int e = 0; e < NEXP; ++e)
            if (e != i1 && acc[t][e] > m2) { m2 = acc[t][e]; i2 = e; }

        // w1 = 1/(1+exp(l2-l1)), w2 = exp(l2-l1)/(1+exp(l2-l1))
        const float e2  = expf(m2 - m1);
        const float inv = 1.0f / (1.0f + e2);
        const float w1  = inv;
        const float w2  = e2 * inv;

        if (lane == 0) {
            const int n = n0 + t;
            float c[8];
            #pragma unroll
            for (int e = 0; e < 8; ++e)
                c[e] = (e == i1) ? w1 : ((e == i2) ? w2 : 0.0f);
            float4* cp = (float4*)(out + (size_t)n * 8);
            cp[0] = make_float4(c[0], c[1], c[2], c[3]);
            cp[1] = make_float4(c[4], c[5], c[6], c[7]);
            float* ip = out + (size_t)N_TOK * 8 + (size_t)n * 2;
            ip[0] = (float)i1;
            ip[1] = (float)i2;
        }
    }
}

extern "C" void kernel_launch(void* const* d_in, const int* in_sizes, int n_in,
                              void* d_out, int out_size, void* d_ws, size_t ws_size,
                              hipStream_t stream) {
    const float* x = (const float*)d_in[0];   // [8192, 4096] f32
    const float* w = (const float*)d_in[1];   // [8, 4096] f32
    float* out = (float*)d_out;

    hipLaunchKernelGGL(router_kernel, dim3(NBLK), dim3(256), 0, stream, x, w, out);
}

// Round 9
// 35.990 us; speedup vs baseline: 1.1626x; 1.1626x over previous
//
#include <hip/hip_runtime.h>
#include <math.h>

#define N_TOK 8192
#define DIM   4096
#define NEXP  8
#define TPW   4                 // tokens per wave, full D per wave
#define ITERS (DIM / 256)       // 16 iterations of 256 floats (lane*4)

// R5 structure + DEEP x pipeline (prefetch distance 3, 4-slot rotation).
// Per-wave in flight: ~12 KB x + 8 KB w -> ~100 KB/CU at 8 waves/CU,
// 4-5x the Little's-law knee (~20 KB/CU) that R1-R6 were stuck at.
// __launch_bounds__(256,2): VGPR cap 256, min 2 waves/SIMD -> the ~180-VGPR
// working set fits with NO spill (R2/R8 failure mode) and occupancy is
// guaranteed 2/SIMD = 8 waves/CU.
//
// VMEM issue-order discipline (vmcnt retires oldest-first):
//   prologue age order: x(0), w(0), x(1), x(2)
//   iter j: issue w(j+1), then x(j+3), then FMA(j) consuming w(j),x(j).
// Waiting for w(j) therefore never drains the younger x prefetches.
__global__ __launch_bounds__(256, 2) void router_kernel(
    const float* __restrict__ x,   // [N_TOK, DIM]
    const float* __restrict__ w,   // [NEXP, DIM]
    float* __restrict__ out)       // [N_TOK*8] combine ++ [N_TOK*2] idx-as-float
{
    const int lane   = threadIdx.x & 63;
    const int waveid = threadIdx.x >> 6;           // 0..3
    const int group  = blockIdx.x * 4 + waveid;    // global wave id
    const int n0     = group * TPW;

    float acc[TPW][NEXP];
    #pragma unroll
    for (int t = 0; t < TPW; ++t)
        #pragma unroll
        for (int e = 0; e < NEXP; ++e) acc[t][e] = 0.0f;

    const float* xp = x + (size_t)n0 * DIM + lane * 4;  // token t at xp + t*DIM
    const float* wp = w + lane * 4;                     // expert e at wp + e*DIM

    float4 xb[4][TPW];   // x: 4-slot rotation, prefetch distance 3
    float4 wb[2][NEXP];  // w: double buffer, prefetch distance 1

    // Prologue — strict age order: x(0), w(0), x(1), x(2)
    #pragma unroll
    for (int t = 0; t < TPW; ++t)
        xb[0][t] = *(const float4*)(xp + (size_t)t * DIM);
    #pragma unroll
    for (int e = 0; e < NEXP; ++e)
        wb[0][e] = *(const float4*)(wp + (size_t)e * DIM);
    #pragma unroll
    for (int t = 0; t < TPW; ++t)
        xb[1][t] = *(const float4*)(xp + (size_t)t * DIM + 256);
    #pragma unroll
    for (int t = 0; t < TPW; ++t)
        xb[2][t] = *(const float4*)(xp + (size_t)t * DIM + 512);

    #pragma unroll   // full unroll: all rotation indices compile-time constant
    for (int j = 0; j < ITERS; ++j) {
        if (j + 1 < ITERS) {                         // issue w(j+1) FIRST
            const int off = (j + 1) * 256;
            #pragma unroll
            for (int e = 0; e < NEXP; ++e)
                wb[(j + 1) & 1][e] = *(const float4*)(wp + (size_t)e * DIM + off);
        }
        if (j + 3 < ITERS) {                         // then x(j+3)
            const int off = (j + 3) * 256;
            #pragma unroll
            for (int t = 0; t < TPW; ++t)
                xb[(j + 3) & 3][t] = *(const float4*)(xp + (size_t)t * DIM + off);
        }

        #pragma unroll                                // consume w(j), x(j)
        for (int t = 0; t < TPW; ++t) {
            const float4 xv = xb[j & 3][t];
            #pragma unroll
            for (int e = 0; e < NEXP; ++e) {
                const float4 wv = wb[j & 1][e];
                acc[t][e] = fmaf(xv.x, wv.x,
                            fmaf(xv.y, wv.y,
                            fmaf(xv.z, wv.z,
                            fmaf(xv.w, wv.w, acc[t][e]))));
            }
        }
    }

    // 64-lane butterfly: every lane ends with the full logit
    #pragma unroll
    for (int t = 0; t < TPW; ++t) {
        #pragma unroll
        for (int e = 0; e < NEXP; ++e) {
            float v = acc[t][e];
            #pragma unroll
            for (int off = 32; off >= 1; off >>= 1)
                v += __shfl_xor(v, off, 64);
            acc[t][e] = v;
        }
    }

    // Epilogue: top-2 + renormalized softmax weights (denominator cancels).
    #pragma unroll
    for (int t = 0; t < TPW; ++t) {
        // argmax: strict >, ascending scan => lowest index wins ties (lax.top_k)
        float m1 = acc[t][0]; int i1 = 0;
        #pragma unroll
        for (int e = 1; e < NEXP; ++e)
            if (acc[t][e] > m1) { m1 = acc[t][e]; i1 = e; }
        float m2 = -INFINITY; int i2 = 0;
        #pragma unroll
        for (int e = 0; e < NEXP; ++e)
            if (e != i1 && acc[t][e] > m2) { m2 = acc[t][e]; i2 = e; }

        // w1 = 1/(1+exp(l2-l1)), w2 = exp(l2-l1)/(1+exp(l2-l1))
        const float e2  = expf(m2 - m1);
        const float inv = 1.0f / (1.0f + e2);
        const float w1  = inv;
        const float w2  = e2 * inv;

        if (lane == 0) {
            const int n = n0 + t;
            float c[8];
            #pragma unroll
            for (int e = 0; e < 8; ++e)
                c[e] = (e == i1) ? w1 : ((e == i2) ? w2 : 0.0f);
            float4* cp = (float4*)(out + (size_t)n * 8);
            cp[0] = make_float4(c[0], c[1], c[2], c[3]);
            cp[1] = make_float4(c[4], c[5], c[6], c[7]);
            float* ip = out + (size_t)N_TOK * 8 + (size_t)n * 2;
            ip[0] = (float)i1;
            ip[1] = (float)i2;
        }
    }
}

extern "C" void kernel_launch(void* const* d_in, const int* in_sizes, int n_in,
                              void* d_out, int out_size, void* d_ws, size_t ws_size,
                              hipStream_t stream) {
    const float* x = (const float*)d_in[0];   // [8192, 4096] f32
    const float* w = (const float*)d_in[1];   // [8, 4096] f32
    float* out = (float*)d_out;

    dim3 grid(N_TOK / (4 * TPW));   // 512 blocks x 4 waves x 4 tokens
    dim3 block(256);
    hipLaunchKernelGGL(router_kernel, grid, block, 0, stream, x, w, out);
}

// Round 10
// 34.707 us; speedup vs baseline: 1.2056x; 1.0370x over previous
//
#include <hip/hip_runtime.h>
#include <math.h>

#define N_TOK 8192
#define DIM   4096
#define NEXP  8
#define TPW   4                  // tokens per wave, FULL D per wave
#define WAVES 8                  // waves per block (512 threads)
#define TPB   (TPW * WAVES)      // 32 tokens per block
#define NBLK  (N_TOK / TPB)      // 256 blocks = 1 per CU
#define ITERS (DIM / 256)        // 16 iterations of 256 floats (lane*4)

// Fused single-kernel router, MSHR-model design:
//  - w (128 KB) staged to LDS once per block; vmcnt then counts ONLY x loads
//    (w reads are lgkmcnt) -> counted x waits never drain the prefetch queue.
//  - 8 waves/CU, each with 12 x-loads (12 KB) in flight: saturates the
//    ~16 KB/CU read-tracking budget that capped all prior rounds at ~4.8 TB/s.
//  - full D per wave -> in-wave butterfly + top-2; no second kernel.
__global__ __launch_bounds__(512, 2) void router_kernel(
    const float* __restrict__ x,   // [N_TOK, DIM]
    const float* __restrict__ w,   // [NEXP, DIM]
    float* __restrict__ out)       // [N_TOK*8] combine ++ [N_TOK*2] idx-as-float
{
    __shared__ float wl[NEXP][DIM];      // 128 KB

    const int tid  = threadIdx.x;
    const int lane = tid & 63;
    const int wid  = tid >> 6;           // 0..7
    const int n0   = blockIdx.x * TPB + wid * TPW;

    // ---- stage all of w -> LDS (16 float4 per thread over 512 threads) ----
    #pragma unroll
    for (int e = 0; e < NEXP; ++e) {
        #pragma unroll
        for (int p = 0; p < 2; ++p) {
            const int pos = p * 2048 + tid * 4;
            *(float4*)&wl[e][pos] = *(const float4*)(w + (size_t)e * DIM + pos);
        }
    }
    __syncthreads();   // the ONLY barrier

    float acc[TPW][NEXP];
    #pragma unroll
    for (int t = 0; t < TPW; ++t)
        #pragma unroll
        for (int e = 0; e < NEXP; ++e) acc[t][e] = 0.0f;

    const float* xp = x + (size_t)n0 * DIM + lane * 4;   // token t at xp + t*DIM

    // x: 4-slot rotation, prefetch distance 3. Prologue: x(0), x(1), x(2).
    float4 xb[4][TPW];
    #pragma unroll
    for (int s = 0; s < 3; ++s)
        #pragma unroll
        for (int t = 0; t < TPW; ++t)
            xb[s][t] = *(const float4*)(xp + (size_t)t * DIM + s * 256);

    #pragma unroll   // full unroll: rotation indices compile-time constant
    for (int j = 0; j < ITERS; ++j) {
        if (j + 3 < ITERS) {                 // issue x(j+3) first (oldest-first queue)
            const int off = (j + 3) * 256;
            #pragma unroll
            for (int t = 0; t < TPW; ++t)
                xb[(j + 3) & 3][t] = *(const float4*)(xp + (size_t)t * DIM + off);
        }

        // w slice j from LDS (lgkmcnt domain; reused across 4 tokens)
        float4 wv[NEXP];
        #pragma unroll
        for (int e = 0; e < NEXP; ++e)
            wv[e] = *(const float4*)&wl[e][j * 256 + lane * 4];

        #pragma unroll                        // consume x(j): vmcnt(12) counted wait
        for (int t = 0; t < TPW; ++t) {
            const float4 xv = xb[j & 3][t];
            #pragma unroll
            for (int e = 0; e < NEXP; ++e) {
                acc[t][e] = fmaf(xv.x, wv[e].x,
                            fmaf(xv.y, wv[e].y,
                            fmaf(xv.z, wv[e].z,
                            fmaf(xv.w, wv[e].w, acc[t][e]))));
            }
        }
    }

    // ---- 64-lane butterfly: every lane ends with the full logit ----
    #pragma unroll
    for (int t = 0; t < TPW; ++t) {
        #pragma unroll
        for (int e = 0; e < NEXP; ++e) {
            float v = acc[t][e];
            #pragma unroll
            for (int off = 32; off >= 1; off >>= 1)
                v += __shfl_xor(v, off, 64);
            acc[t][e] = v;
        }
    }

    // ---- top-2 + renorm (softmax denominator cancels) + store ----
    #pragma unroll
    for (int t = 0; t < TPW; ++t) {
        // argmax: strict >, ascending scan => lowest index wins ties (lax.top_k)
        float m1 = acc[t][0]; int i1 = 0;
        #pragma unroll
        for (int e = 1; e < NEXP; ++e)
            if (acc[t][e] > m1) { m1 = acc[t][e]; i1 = e; }
        float m2 = -INFINITY; int i2 = 0;
        #pragma unroll
        for (int e = 0; e < NEXP; ++e)
            if (e != i1 && acc[t][e] > m2) { m2 = acc[t][e]; i2 = e; }

        // w1 = 1/(1+exp(l2-l1)), w2 = exp(l2-l1)/(1+exp(l2-l1))
        const float e2  = expf(m2 - m1);
        const float inv = 1.0f / (1.0f + e2);
        const float w1  = inv;
        const float w2  = e2 * inv;

        if (lane == 0) {
            const int n = n0 + t;
            float c[8];
            #pragma unroll
            for (int e = 0; e < 8; ++e)
                c[e] = (e == i1) ? w1 : ((e == i2) ? w2 : 0.0f);
            float4* cp = (float4*)(out + (size_t)n * 8);
            cp[0] = make_float4(c[0], c[1], c[2], c[3]);
            cp[1] = make_float4(c[4], c[5], c[6], c[7]);
            float* ip = out + (size_t)N_TOK * 8 + (size_t)n * 2;
            ip[0] = (float)i1;
            ip[1] = (float)i2;
        }
    }
}

extern "C" void kernel_launch(void* const* d_in, const int* in_sizes, int n_in,
                              void* d_out, int out_size, void* d_ws, size_t ws_size,
                              hipStream_t stream) {
    const float* x = (const float*)d_in[0];   // [8192, 4096] f32
    const float* w = (const float*)d_in[1];   // [8, 4096] f32
    float* out = (float*)d_out;

    hipLaunchKernelGGL(router_kernel, dim3(NBLK), dim3(512), 0, stream, x, w, out);
}